// Round 4
// baseline (1817.523 us; speedup 1.0000x reference)
//
#include <hip/hip_runtime.h>
#include <stdint.h>

// NVFP4 Linear fwd: y = dq(rht(x)) @ dq(rht(w))^T + bias
// Round plan:
//  (a) quant: fuse x+w quantization into ONE grid-stride dispatch (2048 blocks).
//  (b) GEMM: ONE window per K-tile (64-MFMA burst), register double-banked
//      frags, 2-tile LDS ring, vmcnt(0)+lgkmcnt(0)+barrier per window (long
//      window => drain is stall-free and publication is airtight).
//      Barriers for the kernel: 256 -> 64.

typedef __bf16 bf16x8 __attribute__((ext_vector_type(8)));
typedef float f32x4 __attribute__((ext_vector_type(4)));

#define AS1 __attribute__((address_space(1)))
#define AS3 __attribute__((address_space(3)))

// ---------------- quantization kernel ----------------

__device__ __forceinline__ float e4m3_rt(float x) {
    unsigned int u = __float_as_uint(x);
    int ex = (int)((u >> 23) & 0xffu) - 127;
    if (ex < -6) ex = -6;                       // subnormal region: step 2^-9
    float qs = __uint_as_float((unsigned)(127 + 3 - ex) << 23);  // 2^(3-ex)
    float qi = __uint_as_float((unsigned)(127 + ex - 3) << 23);  // 2^(ex-3)
    return rintf(x * qs) * qi;                  // exact pow2 scaling, RNE ties-even
}

__device__ __forceinline__ unsigned pack2(float lo, float hi) {
    // exact bf16: low 16 bits of f32 are zero -> truncate
    return (__float_as_uint(lo) >> 16) | (__float_as_uint(hi) & 0xFFFF0000u);
}

__device__ __forceinline__ void quant_group(const float* __restrict__ src,
                                            uint16_t* __restrict__ dst,
                                            float4 s0, float4 s1, float4 s2, float4 s3)
{
    const float4* p = (const float4*)src;
    float4 v0 = p[0], v1 = p[1], v2 = p[2], v3 = p[3];

    float t0 = v0.x * s0.x, t1 = v0.y * s0.y, t2 = v0.z * s0.z, t3 = v0.w * s0.w;
    float t4 = v1.x * s1.x, t5 = v1.y * s1.y, t6 = v1.z * s1.z, t7 = v1.w * s1.w;
    float t8 = v2.x * s2.x, t9 = v2.y * s2.y, t10 = v2.z * s2.z, t11 = v2.w * s2.w;
    float t12 = v3.x * s3.x, t13 = v3.y * s3.y, t14 = v3.z * s3.z, t15 = v3.w * s3.w;

    // FWHT-16, hand-unrolled into named scalars.
#define BT(a, b) { float _s = (a) + (b), _d = (a) - (b); (a) = _s; (b) = _d; }
    BT(t0,t1)  BT(t2,t3)  BT(t4,t5)   BT(t6,t7)
    BT(t8,t9)  BT(t10,t11) BT(t12,t13) BT(t14,t15)
    BT(t0,t2)  BT(t1,t3)  BT(t4,t6)   BT(t5,t7)
    BT(t8,t10) BT(t9,t11) BT(t12,t14) BT(t13,t15)
    BT(t0,t4)  BT(t1,t5)  BT(t2,t6)   BT(t3,t7)
    BT(t8,t12) BT(t9,t13) BT(t10,t14) BT(t11,t15)
    BT(t0,t8)  BT(t1,t9)  BT(t2,t10)  BT(t3,t11)
    BT(t4,t12) BT(t5,t13) BT(t6,t14)  BT(t7,t15)
#undef BT

    t0 *= 0.25f;  t1 *= 0.25f;  t2 *= 0.25f;  t3 *= 0.25f;
    t4 *= 0.25f;  t5 *= 0.25f;  t6 *= 0.25f;  t7 *= 0.25f;
    t8 *= 0.25f;  t9 *= 0.25f;  t10 *= 0.25f; t11 *= 0.25f;
    t12 *= 0.25f; t13 *= 0.25f; t14 *= 0.25f; t15 *= 0.25f;

    float amax = fmaxf(
        fmaxf(fmaxf(fmaxf(fabsf(t0), fabsf(t1)), fmaxf(fabsf(t2), fabsf(t3))),
              fmaxf(fmaxf(fabsf(t4), fabsf(t5)), fmaxf(fabsf(t6), fabsf(t7)))),
        fmaxf(fmaxf(fmaxf(fabsf(t8), fabsf(t9)), fmaxf(fabsf(t10), fabsf(t11))),
              fmaxf(fmaxf(fabsf(t12), fabsf(t13)), fmaxf(fabsf(t14), fabsf(t15)))));

    float scale = e4m3_rt(amax / 6.0f);
    float safe = (scale == 0.0f) ? 1.0f : scale;

    // Exact decision thresholds (3-bit mids x 4-bit e4m3 scale -> exact f32).
    float m1 = 0.25f * safe, m2 = 0.75f * safe, m3 = 1.25f * safe,
          m4 = 1.75f * safe, m5 = 2.5f * safe,  m6 = 3.5f * safe,
          m7 = 5.0f * safe;

#define Q1(tv) ({                                                              \
    float _a = fabsf(tv);                                                      \
    float _q = _a > m5 ? (_a > m7 ? 6.0f : (_a > m6 ? 4.0f : 3.0f))            \
                       : (_a > m3 ? (_a > m4 ? 2.0f : 1.5f)                    \
                                  : (_a > m2 ? 1.0f : (_a > m1 ? 0.5f : 0.0f)));\
    copysignf(_q * scale, (tv)); })

    unsigned w0 = pack2(Q1(t0),  Q1(t1));
    unsigned w1 = pack2(Q1(t2),  Q1(t3));
    unsigned w2 = pack2(Q1(t4),  Q1(t5));
    unsigned w3 = pack2(Q1(t6),  Q1(t7));
    unsigned w4 = pack2(Q1(t8),  Q1(t9));
    unsigned w5 = pack2(Q1(t10), Q1(t11));
    unsigned w6 = pack2(Q1(t12), Q1(t13));
    unsigned w7 = pack2(Q1(t14), Q1(t15));
#undef Q1

    uint4* q4 = (uint4*)dst;
    q4[0] = make_uint4(w0, w1, w2, w3);
    q4[1] = make_uint4(w4, w5, w6, w7);
}

// Fused: one dispatch quantizes both X (ngx groups) and W (ngtot-ngx groups).
__global__ __launch_bounds__(256) void quant_rht_fused(
    const float* __restrict__ X, const float* __restrict__ W,
    const float* __restrict__ signs,
    uint16_t* __restrict__ QX, uint16_t* __restrict__ QW,
    int ngx, int ngtot)
{
    const float4* sp = (const float4*)signs;
    float4 s0 = sp[0], s1 = sp[1], s2 = sp[2], s3 = sp[3];

    for (int gid = blockIdx.x * 256 + threadIdx.x; gid < ngtot;
         gid += gridDim.x * 256) {
        if (gid < ngx)
            quant_group(X + (size_t)gid * 16, QX + (size_t)gid * 16, s0, s1, s2, s3);
        else {
            size_t g = (size_t)(gid - ngx);
            quant_group(W + g * 16, QW + g * 16, s0, s1, s2, s3);
        }
    }
}

// ---------------- GEMM: C[M,N] = A[M,K] * B[N,K]^T + bias[N] ----------------
//
// 256x256 tile, BK=64, 512 threads = 8 waves (2M x 4N), per-wave 128x64 out.
// LDS = 8 slots x 16 KiB = 2-K-tile ring. Tile t (parity P = t&1) occupies
// slots 4P+{0:A-kh0, 1:B-kh0, 2:A-kh1, 3:B-kh1}.
// Chunk swizzle (involution): chunk c = row*4 + kc stored at c ^ ((c>>3)&7);
// gload_lds dest LINEAR, global source inverse-swizzled, ds_read swizzled.
//
// ONE window per K-tile:
//   [STAGE tile t+2 (8 gload_lds, into tile-t's slots: those are DEAD --
//    t's frags entered registers last window, reads drained pre-barrier)]
//   [24 ds_read_b128: tile t+1 frags -> alternate bank]
//   [setprio(1); 64 MFMA on tile-t bank; setprio(0)]
//   [s_waitcnt vmcnt(0) lgkmcnt(0)]  // stage in flight ~full window >> HBM
//   [sched_barrier; s_barrier]       // publishes tile t+2 for ALL waves
// Publication proof: tile t+1 staged at window t-1 top; every wave drains
// vmcnt(0) at t-1 end; barrier; reads at window t. Airtight, no counted gates.

#define BM 256
#define BN 256

__global__ __launch_bounds__(512, 2) void gemm_bt_bias(
    const uint16_t* __restrict__ A,   // bf16 bits, [M,K]
    const uint16_t* __restrict__ B,   // bf16 bits, [N,K]
    const float* __restrict__ bias,   // [N]
    float* __restrict__ C,            // [M,N]
    int M, int N, int K)
{
    __shared__ uint4 sh[8][1024];     // 128 KiB

    const int tid  = threadIdx.x;
    const int lane = tid & 63;
    const int wave = tid >> 6;
    const int wm = wave >> 2, wn = wave & 3;
    const int lm = lane & 15, g4 = lane >> 4;
    const int bn = blockIdx.x, bm = blockIdx.y;

    const int NT = K >> 6;            // K-tiles (BK=64); NT even assumed

    // ---- staging precompute: LDS pos p -> source chunk c = p ^ ((p>>3)&7)
    const int p0 = tid, p1 = 512 + tid;
    const int c0 = p0 ^ ((p0 >> 3) & 7);
    const int c1 = p1 ^ ((p1 >> 3) & 7);
    const uint16_t* asrc0 = A + (size_t)(bm * BM + (c0 >> 2)) * K + (c0 & 3) * 8;
    const uint16_t* asrc1 = A + (size_t)(bm * BM + (c1 >> 2)) * K + (c1 & 3) * 8;
    const uint16_t* bsrc0 = B + (size_t)(bn * BN + (c0 >> 2)) * K + (c0 & 3) * 8;
    const uint16_t* bsrc1 = B + (size_t)(bn * BN + (c1 >> 2)) * K + (c1 & 3) * 8;
    char* ldsd0 = (char*)&sh[0][0] + p0 * 16;
    char* ldsd1 = (char*)&sh[0][0] + p1 * 16;

    // ---- swizzled ds_read chunk positions (per-thread constants)
    int aPos[8], bPos[4];
#pragma unroll
    for (int f = 0; f < 8; ++f) {
        int c = (wm * 128 + f * 16 + lm) * 4 + g4;
        aPos[f] = c ^ ((c >> 3) & 7);
    }
#pragma unroll
    for (int f = 0; f < 4; ++f) {
        int c = (wn * 64 + f * 16 + lm) * 4 + g4;
        bPos[f] = c ^ ((c >> 3) & 7);
    }

    f32x4 acc[8][4];
#pragma unroll
    for (int i = 0; i < 8; ++i)
#pragma unroll
        for (int j = 0; j < 4; ++j) acc[i][j] = (f32x4){0.f, 0.f, 0.f, 0.f};

    // frag double-banks (all indices compile-time after unroll)
    bf16x8 aF[2][2][8];   // [bank][kh][row-frag]
    bf16x8 bF[2][2][4];   // [bank][kh][col-frag]

// Stage tile T2 (parity PAR literal) into slots 4*PAR+{0,1,2,3}.
#define STAGE_P(PAR, T2) do {                                                 \
    int _ko = ((T2) < NT) ? (T2) * 64 : 0;                                    \
    const int _sb = (4 * (PAR)) * 16384;                                      \
    __builtin_amdgcn_global_load_lds((const AS1 unsigned*)(asrc0 + _ko),      \
        (AS3 unsigned*)(ldsd0 + _sb), 16, 0, 0);                              \
    __builtin_amdgcn_global_load_lds((const AS1 unsigned*)(asrc1 + _ko),      \
        (AS3 unsigned*)(ldsd1 + _sb), 16, 0, 0);                              \
    __builtin_amdgcn_global_load_lds((const AS1 unsigned*)(bsrc0 + _ko),      \
        (AS3 unsigned*)(ldsd0 + _sb + 16384), 16, 0, 0);                      \
    __builtin_amdgcn_global_load_lds((const AS1 unsigned*)(bsrc1 + _ko),      \
        (AS3 unsigned*)(ldsd1 + _sb + 16384), 16, 0, 0);                      \
    __builtin_amdgcn_global_load_lds((const AS1 unsigned*)(asrc0 + _ko + 32), \
        (AS3 unsigned*)(ldsd0 + _sb + 32768), 16, 0, 0);                      \
    __builtin_amdgcn_global_load_lds((const AS1 unsigned*)(asrc1 + _ko + 32), \
        (AS3 unsigned*)(ldsd1 + _sb + 32768), 16, 0, 0);                      \
    __builtin_amdgcn_global_load_lds((const AS1 unsigned*)(bsrc0 + _ko + 32), \
        (AS3 unsigned*)(ldsd0 + _sb + 49152), 16, 0, 0);                      \
    __builtin_amdgcn_global_load_lds((const AS1 unsigned*)(bsrc1 + _ko + 32), \
        (AS3 unsigned*)(ldsd1 + _sb + 49152), 16, 0, 0);                      \
} while (0)

// Read tile frags of parity NPAR into bank NB.
#define READS(NB, NPAR) do {                                                  \
    _Pragma("unroll")                                                         \
    for (int _f = 0; _f < 8; ++_f) {                                          \
        aF[NB][0][_f] = __builtin_bit_cast(bf16x8, sh[4*(NPAR)+0][aPos[_f]]); \
        aF[NB][1][_f] = __builtin_bit_cast(bf16x8, sh[4*(NPAR)+2][aPos[_f]]); \
    }                                                                         \
    _Pragma("unroll")                                                         \
    for (int _j = 0; _j < 4; ++_j) {                                          \
        bF[NB][0][_j] = __builtin_bit_cast(bf16x8, sh[4*(NPAR)+1][bPos[_j]]); \
        bF[NB][1][_j] = __builtin_bit_cast(bf16x8, sh[4*(NPAR)+3][bPos[_j]]); \
    }                                                                         \
} while (0)

// One window: compute bank CB (tile T, parity PAR), load bank CB^1 (tile T+1),
// stage tile T+2 (parity PAR).
#define WINDOW(CB, PAR, T) do {                                               \
    STAGE_P(PAR, (T) + 2);                                                    \
    READS(1 - (CB), 1 - (PAR));                                               \
    __builtin_amdgcn_s_setprio(1);                                            \
    _Pragma("unroll")                                                         \
    for (int _kh = 0; _kh < 2; ++_kh)                                         \
        _Pragma("unroll")                                                     \
        for (int _i = 0; _i < 8; ++_i)                                        \
            _Pragma("unroll")                                                 \
            for (int _jj = 0; _jj < 4; ++_jj)                                 \
                acc[_i][_jj] = __builtin_amdgcn_mfma_f32_16x16x32_bf16(       \
                    aF[CB][_kh][_i], bF[CB][_kh][_jj], acc[_i][_jj], 0, 0, 0);\
    __builtin_amdgcn_s_setprio(0);                                            \
    asm volatile("s_waitcnt vmcnt(0) lgkmcnt(0)" ::: "memory");               \
    __builtin_amdgcn_sched_barrier(0);                                        \
    __builtin_amdgcn_s_barrier();                                             \
} while (0)

    // prologue: stage tiles 0,1; tile0 landed (vmcnt(8) leaves tile1's 8 out);
    // barrier publishes tile0; read tile0 frags into bank0; drain everything;
    // barrier (makes window-0's overwrite of tile-0 slots WAR-safe and
    // publishes tile1).
    STAGE_P(0, 0);
    STAGE_P(1, 1);
    asm volatile("s_waitcnt vmcnt(8)" ::: "memory");
    __builtin_amdgcn_s_barrier();
    READS(0, 0);
    asm volatile("s_waitcnt vmcnt(0) lgkmcnt(0)" ::: "memory");
    __builtin_amdgcn_sched_barrier(0);
    __builtin_amdgcn_s_barrier();

    for (int t = 0; t < NT; t += 2) {
        WINDOW(0, 0, t);
        WINDOW(1, 1, t + 1);
    }
    asm volatile("s_waitcnt vmcnt(0) lgkmcnt(0)" ::: "memory");

#undef WINDOW
#undef READS
#undef STAGE_P

    // Epilogue. C/D layout: col = lane&15, row = (lane>>4)*4 + reg  [m89/m91]
#pragma unroll
    for (int j = 0; j < 4; ++j) {
        int col = bn * BN + wn * 64 + j * 16 + lm;
        float bj = bias[col];
#pragma unroll
        for (int i = 0; i < 8; ++i) {
            int row0 = bm * BM + wm * 128 + i * 16 + g4 * 4;
#pragma unroll
            for (int r = 0; r < 4; ++r) {
                C[(size_t)(row0 + r) * (size_t)N + col] = acc[i][j][r] + bj;
            }
        }
    }
}

// ---------------- launch ----------------

extern "C" void kernel_launch(void* const* d_in, const int* in_sizes, int n_in,
                              void* d_out, int out_size, void* d_ws, size_t ws_size,
                              hipStream_t stream)
{
    const float* x        = (const float*)d_in[0];
    const float* w        = (const float*)d_in[1];
    const float* bias     = (const float*)d_in[2];
    const float* signs_in = (const float*)d_in[3];
    // d_in[4] = signs_grad: unused in forward

    const int OUT = in_sizes[2];              // 4096
    const int IN  = in_sizes[1] / OUT;        // 4096
    const int M   = in_sizes[0] / IN;         // 8192

    uint16_t* xq = (uint16_t*)d_ws;                    // [M, IN] bf16
    uint16_t* wq = xq + (size_t)M * (size_t)IN;        // [OUT, IN] bf16
    (void)ws_size; (void)n_in; (void)out_size;

    int ngx = (int)((size_t)M * IN / 16);
    int ngw = (int)((size_t)OUT * IN / 16);
    int ngtot = ngx + ngw;
    quant_rht_fused<<<2048, 256, 0, stream>>>(x, w, signs_in, xq, wq, ngx, ngtot);

    dim3 grid(OUT / BN, M / BM);
    gemm_bt_bias<<<grid, 512, 0, stream>>>(xq, wq, bias, (float*)d_out, M, OUT, IN);
}